// Round 4
// baseline (222.853 us; speedup 1.0000x reference)
//
#include <hip/hip_runtime.h>
#include <hip/hip_bf16.h>

// out[s,b,o] = sum_h in[s,b,h] * w[o,h]
// A = [M=8192, K=1024] fp32, W = [N=4096, K=1024] fp32 (B^T layout), C = [M,N] fp32.
//
// Round 5 -> 6: identical to round 5 (double-barrier 8-phase + LDS-bounce epilogue
// + XCD region map + precomputed ds_read offsets) with the epilogue's cross-lane
// LDS hand-offs hardened: explicit lgkmcnt(0) + sched_barrier(0) between scratch
// writes and reads (and between halves). Cross-lane same-wave LDS exchange is
// invisible to per-thread alias analysis (guide rule #18 class) -- the compiler
// may omit the wait; now it cannot. Round 5's bench died in the container
// (infra-flaky run: push took 465s); this is the same theory re-tested.
//
// Stage-unit ledger (verified passing in round 2's structure):
//   ph1 E.q(0,0) reads A0,B0  stages O.u2    ph2 E.q(0,1) reads B1  stages O.u3
//   ph3 E.q(1,1) reads A1     stages E+2.u1  ph4 E.q(1,0)           stages E+2.u4  GATE vmcnt(4)
//   ph5 O.q(0,0) reads A0,B0  stages E+2.u3  ph6 O.q(0,1) reads B1  stages E+2.u2
//   ph7 O.q(1,1) reads A1     stages E+3.u1  ph8 O.q(1,0)           stages E+3.u4  GATE vmcnt(4)
// Every stage >=2 barriers after its region's last read; each gate leaves 2 units
// (4 loads) in flight, guaranteeing the next tile's 4 units have landed.
// Epilogue: vmcnt(0)+barrier first (in-flight tail stages must not corrupt scratch).

typedef __bf16 bf16x8_t __attribute__((ext_vector_type(8)));
typedef float f32x4_t __attribute__((ext_vector_type(4)));

constexpr int M = 8192;
constexpr int N = 4096;
constexpr int K = 1024;
constexpr int BM = 256;
constexpr int BN = 256;
constexpr int BK = 64;

// ---------------- fp32 -> bf16 convert, both tensors in one launch ----------
__global__ __launch_bounds__(256) void cvt_f32_bf16(const float* __restrict__ a,
                                                    const float* __restrict__ w,
                                                    __bf16* __restrict__ a_bf,
                                                    __bf16* __restrict__ w_bf) {
    size_t i = ((size_t)blockIdx.x * 256 + threadIdx.x) * 8;
    const float* src;
    __bf16* dst;
    if (i < (size_t)M * K) {
        src = a + i;
        dst = a_bf + i;
    } else {
        size_t j = i - (size_t)M * K;
        src = w + j;
        dst = w_bf + j;
    }
    float4 v0 = *(const float4*)(src);
    float4 v1 = *(const float4*)(src + 4);
    bf16x8_t o;
    o[0] = (__bf16)v0.x; o[1] = (__bf16)v0.y; o[2] = (__bf16)v0.z; o[3] = (__bf16)v0.w;
    o[4] = (__bf16)v1.x; o[5] = (__bf16)v1.y; o[6] = (__bf16)v1.z; o[7] = (__bf16)v1.w;
    *(bf16x8_t*)dst = o;
}

// ---------------- bf16 GEMM, 256x256 tile, 8-phase counted-vmcnt pipeline ----
__global__ __launch_bounds__(512, 1) void gemm_bt(const __bf16* __restrict__ A,
                                                  const __bf16* __restrict__ B,
                                                  float* __restrict__ C) {
    // [buf][0=A,1=B][row][col]; row stride 64 bf16 = 128 B = 8 chunks of 16 B.
    // LDS slot (row, chunk c) holds global chunk c ^ (row & 7)  (both-sides involution).
    __shared__ __bf16 lds[2][2][256][BK];   // 128 KiB

    const int tid = threadIdx.x;
    const int lane = tid & 63;
    const int quad = lane >> 4;
    const int l16 = lane & 15;
    const int sa = l16 & 7;            // read-side swizzle key (= frag row & 7)
    const int wave = tid >> 6;         // 8 waves, 2(M) x 4(N)
    const int wm = wave >> 2;
    const int wn = wave & 3;

    // XCD region mapping: linear wgid (x-fastest dispatch) -> region = wgid&7.
    // Region r covers tiles tm in [ (r>>1)*8, +8 ), tn in [ (r&1)*8, +8 ).
    const int wgid = blockIdx.y * gridDim.x + blockIdx.x;   // 0..511
    const int xcd = wgid & 7;
    const int loc = wgid >> 3;                               // 0..63
    const int tm = ((xcd >> 1) << 3) + (loc >> 3);           // 0..31
    const int tn = ((xcd & 1) << 3) + (loc & 7);             // 0..15
    const int bm = tm * BM;
    const int bn = tn * BN;

    // staging per-thread geometry
    const int c8 = tid & 7;            // 16B chunk within a row
    const int r8 = (tid >> 3) & 7;     // dst row & 7 for every stage pattern
    const int scol = (c8 ^ r8) << 3;   // pre-swizzled global source column (elems)
    const int arow = tid >> 3;         // 0..63
    const int bq64 = ((tid >> 8) << 6);// 0 or 64
    const int brow = (tid >> 3) & 31;  // 0..31

    // Precomputed per-lane fragment byte offsets (within one buf).
    // Read addr = ldsBuf + regionConst(imm) + i*2048(imm) + laneOff.
    char* const ldsB0 = (char*)&lds[0][0][0][0];
    char* const ldsB1 = ldsB0 + 65536;
    const int aO0 = (wm * 128 + l16) * 128 + (((0 + quad) ^ sa) << 4);          // ks=0
    const int aO1 = (wm * 128 + l16) * 128 + (((4 + quad) ^ sa) << 4);          // ks=1
    const int bO0 = 32768 + (wn * 64 + l16) * 128 + (((0 + quad) ^ sa) << 4);   // ks=0
    const int bO1 = 32768 + (wn * 64 + l16) * 128 + (((4 + quad) ^ sa) << 4);   // ks=1

    f32x4_t acc[8][4] = {};

#define STAGE_A(buf, mh, k0)                                                        \
  do {                                                                              \
    _Pragma("unroll") for (int r_ = 0; r_ < 2; ++r_) {                              \
      int row_ = r_ * 128 + (mh) * 64 + arow;                                       \
      __builtin_amdgcn_global_load_lds(                                             \
          (const __attribute__((address_space(1))) unsigned int*)(                  \
              A + (size_t)(bm + row_) * K + (k0) + scol),                           \
          (__attribute__((address_space(3))) unsigned int*)(&lds[buf][0][row_][c8 * 8]), \
          16, 0, 0);                                                                \
    }                                                                               \
  } while (0)

#define STAGE_B(buf, nh, k0)                                                        \
  do {                                                                              \
    _Pragma("unroll") for (int r_ = 0; r_ < 2; ++r_) {                              \
      int row_ = r_ * 128 + bq64 + (nh) * 32 + brow;                                \
      __builtin_amdgcn_global_load_lds(                                             \
          (const __attribute__((address_space(1))) unsigned int*)(                  \
              B + (size_t)(bn + row_) * K + (k0) + scol),                           \
          (__attribute__((address_space(3))) unsigned int*)(&lds[buf][1][row_][c8 * 8]), \
          16, 0, 0);                                                                \
    }                                                                               \
  } while (0)

// ldsP: ldsB0 or ldsB1 (compile-time per phase)
#define LOAD_A(ldsP, mh)                                                            \
  do {                                                                              \
    _Pragma("unroll") for (int i_ = 0; i_ < 4; ++i_) {                              \
      a[i_][0] = *(const bf16x8_t*)((ldsP) + (mh) * 8192 + i_ * 2048 + aO0);        \
      a[i_][1] = *(const bf16x8_t*)((ldsP) + (mh) * 8192 + i_ * 2048 + aO1);        \
    }                                                                               \
  } while (0)

#define LOAD_B(ldsP, nh, bv)                                                        \
  do {                                                                              \
    _Pragma("unroll") for (int j_ = 0; j_ < 2; ++j_) {                              \
      bv[j_][0] = *(const bf16x8_t*)((ldsP) + (nh) * 4096 + j_ * 2048 + bO0);       \
      bv[j_][1] = *(const bf16x8_t*)((ldsP) + (nh) * 4096 + j_ * 2048 + bO1);       \
    }                                                                               \
  } while (0)

#define MFMA_Q(mh, nh, bv)                                                          \
  do {                                                                              \
    __builtin_amdgcn_s_setprio(1);                                                  \
    _Pragma("unroll") for (int i_ = 0; i_ < 4; ++i_)                                \
      _Pragma("unroll") for (int j_ = 0; j_ < 2; ++j_) {                            \
        acc[(mh) * 4 + i_][(nh) * 2 + j_] = __builtin_amdgcn_mfma_f32_16x16x32_bf16( \
            a[i_][0], bv[j_][0], acc[(mh) * 4 + i_][(nh) * 2 + j_], 0, 0, 0);       \
        acc[(mh) * 4 + i_][(nh) * 2 + j_] = __builtin_amdgcn_mfma_f32_16x16x32_bf16( \
            a[i_][1], bv[j_][1], acc[(mh) * 4 + i_][(nh) * 2 + j_], 0, 0, 0);       \
      }                                                                             \
    __builtin_amdgcn_s_setprio(0);                                                  \
  } while (0)

#define FENCE() asm volatile("" ::: "memory")
#define BAR()   do { FENCE(); __builtin_amdgcn_s_barrier(); FENCE(); } while (0)
#define LGKM0() asm volatile("s_waitcnt lgkmcnt(0)" ::: "memory")
#define LGKM8() asm volatile("s_waitcnt lgkmcnt(8)" ::: "memory")
#define VMCNT(n_) asm volatile("s_waitcnt vmcnt(" #n_ ")" ::: "memory")
#define SBAR0() __builtin_amdgcn_sched_barrier(0)

    // Prologue: tile0 fully + tile1.{u1,u4}. vmcnt(4) = first 8 of 12 loads landed
    // = all of tile0.
    STAGE_A(0, 0, 0);      // t0.u1
    STAGE_B(0, 0, 0);      // t0.u2
    STAGE_B(0, 1, 0);      // t0.u4
    STAGE_A(0, 1, 0);      // t0.u3
    STAGE_A(1, 0, BK);     // t1.u1
    STAGE_B(1, 1, BK);     // t1.u4
    VMCNT(4);
    BAR();

    bf16x8_t a[4][2], b0[2][2], b1[2][2];

    for (int it = 0; it < 8; ++it) {
        const int kO = it * 128 + 64;
        int kP2 = it * 128 + 128; if (kP2 > K - BK) kP2 = K - BK;  // clamp: garbage into
        int kP3 = it * 128 + 192; if (kP3 > K - BK) kP3 = K - BK;  // dead regions, in-bounds

        // ph1: E q(0,0)
        LOAD_A(ldsB0, 0); LOAD_B(ldsB0, 0, b0);
        STAGE_B(1, 0, kO);
        LGKM8();
        BAR(); LGKM0();
        MFMA_Q(0, 0, b0);
        BAR();

        // ph2: E q(0,1)
        LOAD_B(ldsB0, 1, b1);
        STAGE_A(1, 1, kO);
        BAR(); LGKM0();
        MFMA_Q(0, 1, b1);
        BAR();

        // ph3: E q(1,1)
        LOAD_A(ldsB0, 1);
        STAGE_A(0, 0, kP2);
        BAR(); LGKM0();
        MFMA_Q(1, 1, b1);
        BAR();

        // ph4: E q(1,0); gate for tile O
        STAGE_B(0, 1, kP2);
        BAR();
        MFMA_Q(1, 0, b0);
        VMCNT(4);
        BAR();

        // ph5: O q(0,0)
        LOAD_A(ldsB1, 0); LOAD_B(ldsB1, 0, b0);
        STAGE_A(0, 1, kP2);
        LGKM8();
        BAR(); LGKM0();
        MFMA_Q(0, 0, b0);
        BAR();

        // ph6: O q(0,1)
        LOAD_B(ldsB1, 1, b1);
        STAGE_B(0, 0, kP2);
        BAR(); LGKM0();
        MFMA_Q(0, 1, b1);
        BAR();

        // ph7: O q(1,1)
        LOAD_A(ldsB1, 1);
        STAGE_A(1, 0, kP3);
        BAR(); LGKM0();
        MFMA_Q(1, 1, b1);
        BAR();

        // ph8: O q(1,0); gate for tile E+2
        STAGE_B(1, 1, kP3);
        BAR();
        MFMA_Q(1, 0, b0);
        VMCNT(4);
        BAR();
    }

    // ---------------- epilogue: LDS-bounce to full-line dwordx4 C stores -----
    // Drain in-flight tail stages (they write garbage into lds) before reusing
    // LDS as scratch; barrier so ALL waves' stages are drained.
    VMCNT(0);
    BAR();

    // Per-wave private 16 KiB scratch slot; two 64x64 f32 halves.
    // Cross-lane same-wave hand-off: explicit lgkmcnt(0)+sched_barrier at each
    // write->read and read->overwrite boundary (compiler can't see the cross-lane
    // dependency; rule-18 class hazard).
    float* const sc = (float*)((char*)&lds[0][0][0][0] + wave * 16384);
    const size_t ccol = (size_t)(bn + wn * 64 + (l16 << 2));
#pragma unroll
    for (int h = 0; h < 2; ++h) {
        // acc[h*4+i2][j][r] -> scratch row (i2*16 + quad*4 + r), col (j*16 + l16)
#pragma unroll
        for (int i2 = 0; i2 < 4; ++i2)
#pragma unroll
            for (int j_ = 0; j_ < 4; ++j_)
#pragma unroll
                for (int r_ = 0; r_ < 4; ++r_)
                    sc[(i2 * 16 + quad * 4 + r_) * 64 + j_ * 16 + l16] = acc[h * 4 + i2][j_][r_];
        LGKM0();   // all scratch writes visible before any lane reads
        SBAR0();
#pragma unroll
        for (int rr = 0; rr < 16; ++rr) {
            f32x4_t v = *(const f32x4_t*)((const char*)sc + rr * 1024 + lane * 16);
            int crow = bm + wm * 128 + h * 64 + rr * 4 + (lane >> 4);
            *(f32x4_t*)(&C[(size_t)crow * N + ccol]) = v;
        }
        LGKM0();   // all reads landed before h=1 overwrites the same rows
        SBAR0();
    }

#undef STAGE_A
#undef STAGE_B
#undef LOAD_A
#undef LOAD_B
#undef MFMA_Q
#undef FENCE
#undef BAR
#undef LGKM0
#undef LGKM8
#undef VMCNT
#undef SBAR0
}

extern "C" void kernel_launch(void* const* d_in, const int* in_sizes, int n_in,
                              void* d_out, int out_size, void* d_ws, size_t ws_size,
                              hipStream_t stream) {
    const float* in_f32 = (const float*)d_in[0];   // [M,K]
    const float* w_f32  = (const float*)d_in[1];   // [N,K]
    float* out = (float*)d_out;                     // [M,N]

    __bf16* A_bf = (__bf16*)d_ws;
    __bf16* W_bf = A_bf + (size_t)M * K;

    cvt_f32_bf16<<<((size_t)(M + N) * K) / (8 * 256), 256, 0, stream>>>(in_f32, w_f32, A_bf, W_bf);

    dim3 grid(N / BN, M / BM);   // (16, 32) = 512 blocks, 1 block/CU (128 KiB LDS)
    gemm_bt<<<grid, 512, 0, stream>>>(A_bf, W_bf, out);
}